// Round 1
// baseline (1075.145 us; speedup 1.0000x reference)
//
#include <hip/hip_runtime.h>
#include <cstdint>
#include <cstddef>

// Problem constants
#define VV 50000
#define EE 256
#define HH 512
#define BB 128
#define LL 400
#define TT 100
#define H3 1536

// ---------------------------------------------------------------------------
// Generic tiled fp32 GEMM: C[b][n] = bias[n] + sum_k A[b][k] * W[n][k]
// M is fixed at 128 (the batch). BN=64, BK=32, 256 threads, 8x4 micro-tile.
// Supports two independent jobs selected by blockIdx.y (same N, ldc).
// ---------------------------------------------------------------------------
struct GemmJob {
    const float* A;
    const float* W;
    const float* bias;
    float*       C;
    int          lda;
    int          K;
};

#define GBN 64
#define GBK 32

__global__ __launch_bounds__(256) void gemm_m128(GemmJob j0, GemmJob j1,
                                                 int N, int ldc)
{
    GemmJob j = (blockIdx.y == 0) ? j0 : j1;
    __shared__ float As[GBK][128];
    __shared__ float Wls[GBK][GBN];

    const int tid = threadIdx.x;
    const int n0  = blockIdx.x * GBN;
    const int tx  = tid & 15;   // n dim, 4 outputs each
    const int ty  = tid >> 4;   // b dim, 8 outputs each
    const int kq  = tid & 7;    // float4 index within BK
    const int arow = (tid >> 3) * 4;
    const int wrow = (tid >> 3) * 2;

    float acc[8][4];
    #pragma unroll
    for (int i = 0; i < 8; i++)
        #pragma unroll
        for (int jj = 0; jj < 4; jj++) acc[i][jj] = 0.f;

    for (int k0 = 0; k0 < j.K; k0 += GBK) {
        // Stage A tile (128 x 32), transposed into As[k][b]
        #pragma unroll
        for (int i = 0; i < 4; i++) {
            const float4 v = *(const float4*)(j.A + (size_t)(arow + i) * j.lda + k0 + kq * 4);
            As[kq*4+0][arow+i] = v.x;
            As[kq*4+1][arow+i] = v.y;
            As[kq*4+2][arow+i] = v.z;
            As[kq*4+3][arow+i] = v.w;
        }
        // Stage W tile (64 x 32), transposed into Wls[k][n]
        #pragma unroll
        for (int i = 0; i < 2; i++) {
            const int n = n0 + wrow + i;
            float4 v = make_float4(0.f, 0.f, 0.f, 0.f);
            if (n < N) v = *(const float4*)(j.W + (size_t)n * j.K + k0 + kq * 4);
            Wls[kq*4+0][wrow+i] = v.x;
            Wls[kq*4+1][wrow+i] = v.y;
            Wls[kq*4+2][wrow+i] = v.z;
            Wls[kq*4+3][wrow+i] = v.w;
        }
        __syncthreads();
        #pragma unroll
        for (int kk = 0; kk < GBK; kk++) {
            float a[8], w[4];
            #pragma unroll
            for (int i = 0; i < 8; i++) a[i] = As[kk][ty*8+i];
            #pragma unroll
            for (int jj = 0; jj < 4; jj++) w[jj] = Wls[kk][tx*4+jj];
            #pragma unroll
            for (int i = 0; i < 8; i++)
                #pragma unroll
                for (int jj = 0; jj < 4; jj++)
                    acc[i][jj] += a[i] * w[jj];
        }
        __syncthreads();
    }

    // Store with bias
    const int nbase = n0 + tx * 4;
    #pragma unroll
    for (int i = 0; i < 8; i++) {
        const int b = ty * 8 + i;
        if (nbase + 3 < N) {
            const float4 bb = *(const float4*)(j.bias + nbase);
            float4 r;
            r.x = acc[i][0] + bb.x;
            r.y = acc[i][1] + bb.y;
            r.z = acc[i][2] + bb.z;
            r.w = acc[i][3] + bb.w;
            *(float4*)(j.C + (size_t)b * ldc + nbase) = r;
        } else {
            #pragma unroll
            for (int jj = 0; jj < 4; jj++) {
                const int n = nbase + jj;
                if (n < N) j.C[(size_t)b * ldc + n] = acc[i][jj] + j.bias[n];
            }
        }
    }
}

// ---------------------------------------------------------------------------
// Embedding gather: x[b][:] = emb[inputs[b]][:]
// ---------------------------------------------------------------------------
__global__ __launch_bounds__(256) void gather_emb(const int* __restrict__ tok,
                                                  const float* __restrict__ emb,
                                                  float* __restrict__ x)
{
    const int b = blockIdx.x;
    x[(size_t)b * EE + threadIdx.x] = emb[(size_t)tok[b] * EE + threadIdx.x];
}

// Zero the c_t_e / c_t_d slices of new_hidden (atomicAdd targets)
__global__ __launch_bounds__(256) void zero_ctx(float* __restrict__ nh)
{
    float* p = nh + (size_t)blockIdx.x * H3;
    const int tid = threadIdx.x;
    p[tid] = 0.f;  p[tid + 256] = 0.f;
    p[1024 + tid] = 0.f;  p[1280 + tid] = 0.f;
}

// ---------------------------------------------------------------------------
// GRU pointwise combine
// ---------------------------------------------------------------------------
__global__ __launch_bounds__(256) void gru_combine(const float* __restrict__ gi,
                                                   const float* __restrict__ gh,
                                                   const float* __restrict__ hprev,
                                                   float* __restrict__ nh,
                                                   float* __restrict__ out_h)
{
    const int b = blockIdx.x;
    const int tid = threadIdx.x;
    #pragma unroll
    for (int r = 0; r < 2; r++) {
        const int i = tid + r * 256;
        const size_t base = (size_t)b * H3;
        const float ir = gi[base + i],        hr = gh[base + i];
        const float iz = gi[base + 512 + i],  hz = gh[base + 512 + i];
        const float in_ = gi[base + 1024 + i], hn = gh[base + 1024 + i];
        const float rr = 1.f / (1.f + expf(-(ir + hr)));
        const float zz = 1.f / (1.f + expf(-(iz + hz)));
        const float nn = tanhf(in_ + rr * hn);
        const float hp = hprev[(size_t)b * HH + i];
        const float h  = (1.f - zz) * nn + zz * hp;
        nh[base + 512 + i] = h;
        out_h[(size_t)b * HH + i] = h;
    }
}

// ---------------------------------------------------------------------------
// Attention scores: out[b][l] = dot(q[b][:], ctx[l][b][:])  (+ length mask)
// One wave per (b, l). grid = (Lc/4, B), 256 threads (4 waves).
// ---------------------------------------------------------------------------
__global__ __launch_bounds__(256) void attn_scores(const float* __restrict__ q,
                                                   const float* __restrict__ ctx,
                                                   const int* __restrict__ lens,
                                                   float* __restrict__ out,
                                                   int Lc)
{
    const int b = blockIdx.y;
    const int wave = threadIdx.x >> 6;
    const int lane = threadIdx.x & 63;
    const int l = blockIdx.x * 4 + wave;
    const float* t = q + (size_t)b * HH;
    const float* c = ctx + ((size_t)l * BB + b) * HH;
    float s = 0.f;
    #pragma unroll
    for (int jj = 0; jj < 8; jj++)
        s += t[lane + jj * 64] * c[lane + jj * 64];
    #pragma unroll
    for (int off = 32; off; off >>= 1)
        s += __shfl_down(s, off);
    if (lane == 0) {
        if (lens && (Lc < lens[b]) && (l >= lens[b])) s = -__builtin_inff();
        out[(size_t)b * Lc + l] = s;
    }
}

// In-place row softmax for both alpha_e (y=0) and alpha_d (y=1)
__global__ __launch_bounds__(256) void softmax2(float* __restrict__ ae, int ne,
                                                float* __restrict__ ad, int nd)
{
    __shared__ float red[256];
    const int tid = threadIdx.x;
    float* row;
    int n;
    if (blockIdx.y == 0) { row = ae + (size_t)blockIdx.x * ne; n = ne; }
    else                 { row = ad + (size_t)blockIdx.x * nd; n = nd; }

    float m = -__builtin_inff();
    for (int i = tid; i < n; i += 256) m = fmaxf(m, row[i]);
    red[tid] = m; __syncthreads();
    for (int s = 128; s; s >>= 1) {
        if (tid < s) red[tid] = fmaxf(red[tid], red[tid + s]);
        __syncthreads();
    }
    m = red[0]; __syncthreads();

    float sum = 0.f;
    for (int i = tid; i < n; i += 256) sum += expf(row[i] - m);
    red[tid] = sum; __syncthreads();
    for (int s = 128; s; s >>= 1) {
        if (tid < s) red[tid] += red[tid + s];
        __syncthreads();
    }
    const float inv = 1.f / red[0];
    for (int i = tid; i < n; i += 256) row[i] = expf(row[i] - m) * inv;
}

// Context vector: dst[b][off+h] += sum_{l in chunk} alpha[b][l] * ctx[l][b][h]
__global__ __launch_bounds__(256) void attn_context(const float* __restrict__ alpha,
                                                    const float* __restrict__ ctx,
                                                    float* __restrict__ dst,
                                                    int Lc, int chunk, int off)
{
    __shared__ float al[128];
    const int b = blockIdx.y;
    const int l0 = blockIdx.x * chunk;
    const int tid = threadIdx.x;
    for (int i = tid; i < chunk; i += 256) al[i] = alpha[(size_t)b * Lc + l0 + i];
    __syncthreads();
    float a0 = 0.f, a1 = 0.f;
    for (int ll = 0; ll < chunk; ll++) {
        const float* c = ctx + ((size_t)(l0 + ll) * BB + b) * HH;
        const float w = al[ll];
        a0 += w * c[tid];
        a1 += w * c[tid + 256];
    }
    atomicAdd(&dst[(size_t)b * H3 + off + tid], a0);
    atomicAdd(&dst[(size_t)b * H3 + off + tid + 256], a1);
}

// pointer_prob[b] = dot(nh[b][:], W_ptr) + b_ptr
__global__ __launch_bounds__(256) void pointer_kernel(const float* __restrict__ nh,
                                                      const float* __restrict__ W_ptr,
                                                      const float* __restrict__ b_ptr,
                                                      float* __restrict__ pp)
{
    __shared__ float red[256];
    const int b = blockIdx.x;
    const int tid = threadIdx.x;
    float s = 0.f;
    for (int jj = tid; jj < H3; jj += 256) s += nh[(size_t)b * H3 + jj] * W_ptr[jj];
    red[tid] = s; __syncthreads();
    for (int t = 128; t; t >>= 1) {
        if (tid < t) red[tid] += red[tid + t];
        __syncthreads();
    }
    if (tid == 0) pp[b] = red[0] + b_ptr[0];
}

// Row logsumexp over the logits (which live in d_out at this point)
__global__ __launch_bounds__(256) void logsumexp_rows(const float* __restrict__ logits,
                                                      float* __restrict__ lse)
{
    __shared__ float rm[256], rs[256];
    const int b = blockIdx.x;
    const int tid = threadIdx.x;
    const float* row = logits + (size_t)b * VV;
    float m = -__builtin_inff(), s = 0.f;
    for (int i = tid; i < VV; i += 256) {
        const float x = row[i];
        if (x > m) { s = s * expf(m - x) + 1.f; m = x; }
        else       { s += expf(x - m); }
    }
    rm[tid] = m; rs[tid] = s; __syncthreads();
    for (int t = 128; t; t >>= 1) {
        if (tid < t) {
            const float m2 = rm[tid + t], s2 = rs[tid + t];
            const float M = fmaxf(rm[tid], m2);
            rs[tid] = rs[tid] * expf(rm[tid] - M) + s2 * expf(m2 - M);
            rm[tid] = M;
        }
        __syncthreads();
    }
    if (tid == 0) lse[b] = rm[0] + logf(rs[0]);
}

// In-place: out[b][v] = (1 - pp[b]) * (logit - lse[b])
__global__ __launch_bounds__(256) void final_write(float* __restrict__ out,
                                                   const float* __restrict__ pp,
                                                   const float* __restrict__ lse)
{
    const int b = blockIdx.y;
    const int v = (blockIdx.x * 256 + threadIdx.x) * 4;
    if (v >= VV) return;
    float4* p = (float4*)(out + (size_t)b * VV + v);
    float4 x = *p;
    const float g = 1.f - pp[b];
    const float Lse = lse[b];
    x.x = g * (x.x - Lse);
    x.y = g * (x.y - Lse);
    x.z = g * (x.z - Lse);
    x.w = g * (x.w - Lse);
    *p = x;
}

// Scatter pointer mass: out[b][enc_in[l][b]] += pp[b] * alpha_e[b][l]
__global__ __launch_bounds__(256) void scatter_pointer(float* __restrict__ out,
                                                       const float* __restrict__ pp,
                                                       const float* __restrict__ alpha_e,
                                                       const int* __restrict__ enc_in)
{
    const int idx = blockIdx.x * 256 + threadIdx.x;
    if (idx >= BB * LL) return;
    const int b = idx / LL;
    const int l = idx - b * LL;
    const int tok = enc_in[(size_t)l * BB + b];
    atomicAdd(&out[(size_t)b * VV + tok], pp[b] * alpha_e[idx]);
}

// previous_weights passthrough
__global__ __launch_bounds__(256) void copy_pw(float* __restrict__ dst,
                                               const float* __restrict__ src)
{
    const int idx = blockIdx.x * 256 + threadIdx.x;
    if (idx < BB * LL) dst[idx] = src[idx];
}

// ---------------------------------------------------------------------------
extern "C" void kernel_launch(void* const* d_in, const int* in_sizes, int n_in,
                              void* d_out, int out_size, void* d_ws, size_t ws_size,
                              hipStream_t stream)
{
    const int*   inputs  = (const int*)  d_in[0];
    const float* hidden  = (const float*)d_in[1];
    const float* enc_h   = (const float*)d_in[2];
    const int*   enc_len = (const int*)  d_in[3];
    const float* prev_w  = (const float*)d_in[4];
    const float* dec_h   = (const float*)d_in[5];
    const int*   enc_in  = (const int*)  d_in[6];
    // d_in[7] = time_step (unused by the reference body)
    const float* emb     = (const float*)d_in[8];
    const float* W_ih    = (const float*)d_in[9];
    const float* W_hh    = (const float*)d_in[10];
    const float* b_ih    = (const float*)d_in[11];
    const float* b_hh    = (const float*)d_in[12];
    const float* W_ae    = (const float*)d_in[13];
    const float* b_ae    = (const float*)d_in[14];
    const float* W_ad    = (const float*)d_in[15];
    const float* b_ad    = (const float*)d_in[16];
    const float* W_ptr   = (const float*)d_in[17];
    const float* b_ptr   = (const float*)d_in[18];
    const float* W_out   = (const float*)d_in[19];
    const float* b_out   = (const float*)d_in[20];

    float* out = (float*)d_out;
    float* out_final = out;                              // B*V
    float* out_h     = out + (size_t)BB * VV;            // B*H
    float* out_pw    = out_h + (size_t)BB * HH;          // B*L

    // Workspace layout (floats)
    float* ws  = (float*)d_ws;
    float* X   = ws;                 // B*E      = 32768
    float* GI  = X   + BB * EE;      // B*3H     = 196608
    float* GH  = GI  + BB * H3;      // B*3H
    float* TE  = GH  + BB * H3;      // B*H
    float* TD  = TE  + BB * HH;      // B*H
    float* AE  = TD  + BB * HH;      // B*L
    float* AD  = AE  + BB * LL;      // B*T
    float* NH  = AD  + BB * TT;      // B*3H  (c_t_e | h | c_t_d)
    float* PP  = NH  + BB * H3;      // B
    float* LSE = PP  + BB;           // B

    // 1. embedding gather + zero context slices
    gather_emb<<<BB, 256, 0, stream>>>(inputs, emb, X);
    zero_ctx<<<BB, 256, 0, stream>>>(NH);

    // 2. GRU gate GEMMs (paired in one launch)
    {
        GemmJob jgi{X,      W_ih, b_ih, GI, EE, EE};
        GemmJob jgh{hidden, W_hh, b_hh, GH, HH, HH};
        gemm_m128<<<dim3(H3 / GBN, 2), 256, 0, stream>>>(jgi, jgh, H3, H3);
    }
    // 3. GRU combine -> h (into NH middle slice and output 1)
    gru_combine<<<BB, 256, 0, stream>>>(GI, GH, hidden, NH, out_h);

    // 4. attention query projections te/td (paired)
    {
        GemmJob jte{NH + 512, W_ae, b_ae, TE, H3, HH};
        GemmJob jtd{NH + 512, W_ad, b_ad, TD, H3, HH};
        gemm_m128<<<dim3(HH / GBN, 2), 256, 0, stream>>>(jte, jtd, HH, HH);
    }

    // 5. attention scores
    attn_scores<<<dim3(LL / 4, BB), 256, 0, stream>>>(TE, enc_h, enc_len, AE, LL);
    attn_scores<<<dim3(TT / 4, BB), 256, 0, stream>>>(TD, dec_h, nullptr, AD, TT);

    // 6. softmaxes (both in one launch)
    softmax2<<<dim3(BB, 2), 256, 0, stream>>>(AE, LL, AD, TT);

    // 7. context vectors -> NH slices 0 and 1024
    attn_context<<<dim3(4, BB), 256, 0, stream>>>(AE, enc_h, NH, LL, 100, 0);
    attn_context<<<dim3(2, BB), 256, 0, stream>>>(AD, dec_h, NH, TT, 50, 1024);

    // 8. pointer prob
    pointer_kernel<<<BB, 256, 0, stream>>>(NH, W_ptr, b_ptr, PP);

    // 9. vocab GEMM -> logits straight into d_out
    {
        GemmJob jo{NH, W_out, b_out, out_final, H3, H3};
        gemm_m128<<<dim3((VV + GBN - 1) / GBN, 1), 256, 0, stream>>>(jo, jo, VV, VV);
    }

    // 10. log-softmax stats, then in-place final combine
    logsumexp_rows<<<BB, 256, 0, stream>>>(out_final, LSE);
    final_write<<<dim3((VV / 4 + 255) / 256, BB), 256, 0, stream>>>(out_final, PP, LSE);

    // 11. pointer scatter-add
    scatter_pointer<<<(BB * LL) / 256, 256, 0, stream>>>(out_final, PP, AE, enc_in);

    // 12. previous_weights passthrough
    copy_pw<<<(BB * LL) / 256, 256, 0, stream>>>(out_pw, prev_w);
}

// Round 2
// 907.607 us; speedup vs baseline: 1.1846x; 1.1846x over previous
//
#include <hip/hip_runtime.h>
#include <cstdint>
#include <cstddef>

// Problem constants
#define VV 50000
#define EE 256
#define HH 512
#define BB 128
#define LL 400
#define TT 100
#define H3 1536

typedef __attribute__((ext_vector_type(8))) short short8;
typedef __attribute__((ext_vector_type(4))) float floatx4;

__device__ __forceinline__ unsigned short f2bf(float x) {
    union { float f; unsigned u; } v; v.f = x;
    unsigned r = v.u + 0x7fffu + ((v.u >> 16) & 1u);
    return (unsigned short)(r >> 16);
}

// ---------------------------------------------------------------------------
// Small fp32 GEMM (GRU gates, attention projections): C = bias + A * W^T
// M fixed 128. BN=64, BK=32, 256 threads, 8x4 micro-tile. Two jobs per grid.
// ---------------------------------------------------------------------------
struct GemmJob {
    const float* A;
    const float* W;
    const float* bias;
    float*       C;
    int          lda;
    int          K;
};

#define GBN 64
#define GBK 32

__global__ __launch_bounds__(256) void gemm_m128(GemmJob j0, GemmJob j1,
                                                 int N, int ldc)
{
    GemmJob j = (blockIdx.y == 0) ? j0 : j1;
    __shared__ float As[GBK][128];
    __shared__ float Wls[GBK][GBN];

    const int tid = threadIdx.x;
    const int n0  = blockIdx.x * GBN;
    const int tx  = tid & 15;
    const int ty  = tid >> 4;
    const int kq  = tid & 7;
    const int arow = (tid >> 3) * 4;
    const int wrow = (tid >> 3) * 2;

    float acc[8][4];
    #pragma unroll
    for (int i = 0; i < 8; i++)
        #pragma unroll
        for (int jj = 0; jj < 4; jj++) acc[i][jj] = 0.f;

    for (int k0 = 0; k0 < j.K; k0 += GBK) {
        #pragma unroll
        for (int i = 0; i < 4; i++) {
            const float4 v = *(const float4*)(j.A + (size_t)(arow + i) * j.lda + k0 + kq * 4);
            As[kq*4+0][arow+i] = v.x;
            As[kq*4+1][arow+i] = v.y;
            As[kq*4+2][arow+i] = v.z;
            As[kq*4+3][arow+i] = v.w;
        }
        #pragma unroll
        for (int i = 0; i < 2; i++) {
            const int n = n0 + wrow + i;
            float4 v = make_float4(0.f, 0.f, 0.f, 0.f);
            if (n < N) v = *(const float4*)(j.W + (size_t)n * j.K + k0 + kq * 4);
            Wls[kq*4+0][wrow+i] = v.x;
            Wls[kq*4+1][wrow+i] = v.y;
            Wls[kq*4+2][wrow+i] = v.z;
            Wls[kq*4+3][wrow+i] = v.w;
        }
        __syncthreads();
        #pragma unroll
        for (int kk = 0; kk < GBK; kk++) {
            float a[8], w[4];
            #pragma unroll
            for (int i = 0; i < 8; i++) a[i] = As[kk][ty*8+i];
            #pragma unroll
            for (int jj = 0; jj < 4; jj++) w[jj] = Wls[kk][tx*4+jj];
            #pragma unroll
            for (int i = 0; i < 8; i++)
                #pragma unroll
                for (int jj = 0; jj < 4; jj++)
                    acc[i][jj] += a[i] * w[jj];
        }
        __syncthreads();
    }

    const int nbase = n0 + tx * 4;
    #pragma unroll
    for (int i = 0; i < 8; i++) {
        const int b = ty * 8 + i;
        if (nbase + 3 < N) {
            const float4 bb = *(const float4*)(j.bias + nbase);
            float4 r;
            r.x = acc[i][0] + bb.x;
            r.y = acc[i][1] + bb.y;
            r.z = acc[i][2] + bb.z;
            r.w = acc[i][3] + bb.w;
            *(float4*)(j.C + (size_t)b * ldc + nbase) = r;
        } else {
            #pragma unroll
            for (int jj = 0; jj < 4; jj++) {
                const int n = nbase + jj;
                if (n < N) j.C[(size_t)b * ldc + n] = acc[i][jj] + j.bias[n];
            }
        }
    }
}

// ---------------------------------------------------------------------------
// Vocab GEMM: bf16 MFMA, no LDS. C[m][n] = bias[n] + sum_k A[m][k]*W[n][k]
// A: [128][1536] bf16 (pre-converted, cached in L1/L2).
// W: [V][1536] f32 from HBM, converted in-register.
// Block = 256 threads = 4 waves; wave handles a 16-wide n strip, all 128 m.
// ---------------------------------------------------------------------------
__global__ __launch_bounds__(256) void vocab_mfma(const unsigned short* __restrict__ A,
                                                  const float* __restrict__ W,
                                                  const float* __restrict__ bias,
                                                  float* __restrict__ C)
{
    const int wave = threadIdx.x >> 6;
    const int lane = threadIdx.x & 63;
    const int quad = lane >> 4;   // 0..3
    const int nl   = lane & 15;
    const int n    = blockIdx.x * 64 + wave * 16 + nl;
    const int nc   = (n < VV) ? n : (VV - 1);

    floatx4 acc[8];
    #pragma unroll
    for (int i = 0; i < 8; i++) acc[i] = (floatx4){0.f, 0.f, 0.f, 0.f};

    const float* wp = W + (size_t)nc * H3 + quad * 8;
    const unsigned short* ap = A + (size_t)nl * H3 + quad * 8;

    for (int k0 = 0; k0 < H3; k0 += 32) {
        const float4 w0 = *(const float4*)(wp + k0);
        const float4 w1 = *(const float4*)(wp + k0 + 4);
        short8 bfrag;
        bfrag[0] = (short)f2bf(w0.x);
        bfrag[1] = (short)f2bf(w0.y);
        bfrag[2] = (short)f2bf(w0.z);
        bfrag[3] = (short)f2bf(w0.w);
        bfrag[4] = (short)f2bf(w1.x);
        bfrag[5] = (short)f2bf(w1.y);
        bfrag[6] = (short)f2bf(w1.z);
        bfrag[7] = (short)f2bf(w1.w);
        #pragma unroll
        for (int mt = 0; mt < 8; mt++) {
            const short8 af = *(const short8*)(ap + (size_t)mt * 16 * H3 + k0);
            acc[mt] = __builtin_amdgcn_mfma_f32_16x16x32_bf16(af, bfrag, acc[mt], 0, 0, 0);
        }
    }

    if (n < VV) {
        const float bv = bias[n];
        #pragma unroll
        for (int mt = 0; mt < 8; mt++) {
            #pragma unroll
            for (int r = 0; r < 4; r++) {
                const int m = mt * 16 + quad * 4 + r;
                C[(size_t)m * VV + n] = acc[mt][r] + bv;
            }
        }
    }
}

// NH (f32) -> bf16 bits
__global__ __launch_bounds__(256) void nh_to_bf16(const float* __restrict__ nh,
                                                  unsigned short* __restrict__ out)
{
    const int idx = blockIdx.x * 256 + threadIdx.x;
    out[idx] = f2bf(nh[idx]);
}

// ---------------------------------------------------------------------------
// Embedding gather
// ---------------------------------------------------------------------------
__global__ __launch_bounds__(256) void gather_emb(const int* __restrict__ tok,
                                                  const float* __restrict__ emb,
                                                  float* __restrict__ x)
{
    const int b = blockIdx.x;
    x[(size_t)b * EE + threadIdx.x] = emb[(size_t)tok[b] * EE + threadIdx.x];
}

__global__ __launch_bounds__(256) void zero_ctx(float* __restrict__ nh)
{
    float* p = nh + (size_t)blockIdx.x * H3;
    const int tid = threadIdx.x;
    p[tid] = 0.f;  p[tid + 256] = 0.f;
    p[1024 + tid] = 0.f;  p[1280 + tid] = 0.f;
}

// ---------------------------------------------------------------------------
// GRU pointwise combine
// ---------------------------------------------------------------------------
__global__ __launch_bounds__(256) void gru_combine(const float* __restrict__ gi,
                                                   const float* __restrict__ gh,
                                                   const float* __restrict__ hprev,
                                                   float* __restrict__ nh,
                                                   float* __restrict__ out_h)
{
    const int b = blockIdx.x;
    const int tid = threadIdx.x;
    #pragma unroll
    for (int r = 0; r < 2; r++) {
        const int i = tid + r * 256;
        const size_t base = (size_t)b * H3;
        const float ir = gi[base + i],        hr = gh[base + i];
        const float iz = gi[base + 512 + i],  hz = gh[base + 512 + i];
        const float in_ = gi[base + 1024 + i], hn = gh[base + 1024 + i];
        const float rr = 1.f / (1.f + expf(-(ir + hr)));
        const float zz = 1.f / (1.f + expf(-(iz + hz)));
        const float nn = tanhf(in_ + rr * hn);
        const float hp = hprev[(size_t)b * HH + i];
        const float h  = (1.f - zz) * nn + zz * hp;
        nh[base + 512 + i] = h;
        out_h[(size_t)b * HH + i] = h;
    }
}

// ---------------------------------------------------------------------------
// Attention scores (float4 loads): out[b][l] = dot(q[b], ctx[l][b]) + mask
// ---------------------------------------------------------------------------
__global__ __launch_bounds__(256) void attn_scores(const float* __restrict__ q,
                                                   const float* __restrict__ ctx,
                                                   const int* __restrict__ lens,
                                                   float* __restrict__ out,
                                                   int Lc)
{
    const int b = blockIdx.y;
    const int wave = threadIdx.x >> 6;
    const int lane = threadIdx.x & 63;
    const int l = blockIdx.x * 4 + wave;
    const float4* q4 = (const float4*)(q + (size_t)b * HH);
    const float4* c4 = (const float4*)(ctx + ((size_t)l * BB + b) * HH);
    const float4 a0 = q4[lane],      b0 = c4[lane];
    const float4 a1 = q4[lane + 64], b1 = c4[lane + 64];
    float s = a0.x*b0.x + a0.y*b0.y + a0.z*b0.z + a0.w*b0.w
            + a1.x*b1.x + a1.y*b1.y + a1.z*b1.z + a1.w*b1.w;
    #pragma unroll
    for (int off = 32; off; off >>= 1)
        s += __shfl_down(s, off);
    if (lane == 0) {
        if (lens && (Lc < lens[b]) && (l >= lens[b])) s = -__builtin_inff();
        out[(size_t)b * Lc + l] = s;
    }
}

// In-place row softmax for alpha_e (y=0) and alpha_d (y=1)
__global__ __launch_bounds__(256) void softmax2(float* __restrict__ ae, int ne,
                                                float* __restrict__ ad, int nd)
{
    __shared__ float red[256];
    const int tid = threadIdx.x;
    float* row;
    int n;
    if (blockIdx.y == 0) { row = ae + (size_t)blockIdx.x * ne; n = ne; }
    else                 { row = ad + (size_t)blockIdx.x * nd; n = nd; }

    float m = -__builtin_inff();
    for (int i = tid; i < n; i += 256) m = fmaxf(m, row[i]);
    red[tid] = m; __syncthreads();
    for (int s = 128; s; s >>= 1) {
        if (tid < s) red[tid] = fmaxf(red[tid], red[tid + s]);
        __syncthreads();
    }
    m = red[0]; __syncthreads();

    float sum = 0.f;
    for (int i = tid; i < n; i += 256) sum += expf(row[i] - m);
    red[tid] = sum; __syncthreads();
    for (int s = 128; s; s >>= 1) {
        if (tid < s) red[tid] += red[tid + s];
        __syncthreads();
    }
    const float inv = 1.f / red[0];
    for (int i = tid; i < n; i += 256) row[i] = expf(row[i] - m) * inv;
}

// Context vector (chunked): dst[b][off+*] += sum_{l in chunk} alpha[b][l]*ctx[l][b][*]
__global__ __launch_bounds__(256) void attn_context(const float* __restrict__ alpha,
                                                    const float* __restrict__ ctx,
                                                    float* __restrict__ dst,
                                                    int Lc, int chunk, int off)
{
    __shared__ float al[32];
    const int b = blockIdx.y;
    const int l0 = blockIdx.x * chunk;
    const int tid = threadIdx.x;
    if (tid < chunk) al[tid] = alpha[(size_t)b * Lc + l0 + tid];
    __syncthreads();
    float ax = 0.f, ay = 0.f;
    for (int ll = 0; ll < chunk; ll++) {
        const float2* c = (const float2*)(ctx + ((size_t)(l0 + ll) * BB + b) * HH);
        const float2 v = c[tid];
        const float w = al[ll];
        ax += w * v.x;
        ay += w * v.y;
    }
    atomicAdd(&dst[(size_t)b * H3 + off + tid * 2 + 0], ax);
    atomicAdd(&dst[(size_t)b * H3 + off + tid * 2 + 1], ay);
}

// pointer_prob[b] = dot(nh[b], W_ptr) + b_ptr
__global__ __launch_bounds__(256) void pointer_kernel(const float* __restrict__ nh,
                                                      const float* __restrict__ W_ptr,
                                                      const float* __restrict__ b_ptr,
                                                      float* __restrict__ pp)
{
    __shared__ float red[256];
    const int b = blockIdx.x;
    const int tid = threadIdx.x;
    float s = 0.f;
    for (int jj = tid; jj < H3; jj += 256) s += nh[(size_t)b * H3 + jj] * W_ptr[jj];
    red[tid] = s; __syncthreads();
    for (int t = 128; t; t >>= 1) {
        if (tid < t) red[tid] += red[tid + t];
        __syncthreads();
    }
    if (tid == 0) pp[b] = red[0] + b_ptr[0];
}

// ---------------------------------------------------------------------------
// Two-stage logsumexp over V
// ---------------------------------------------------------------------------
#define LSE_CHUNKS 10
#define LSE_SPAN 5000   // 1250 float4s

__global__ __launch_bounds__(256) void lse_part(const float* __restrict__ logits,
                                                float2* __restrict__ part)
{
    __shared__ float rm[256], rs[256];
    const int b = blockIdx.y;
    const int s = blockIdx.x;
    const int tid = threadIdx.x;
    const float4* row = (const float4*)(logits + (size_t)b * VV + (size_t)s * LSE_SPAN);
    float m = -__builtin_inff(), sum = 0.f;
    for (int i = tid; i < LSE_SPAN / 4; i += 256) {
        const float4 v = row[i];
        const float mx = fmaxf(fmaxf(v.x, v.y), fmaxf(v.z, v.w));
        if (mx > m) { sum *= expf(m - mx); m = mx; }
        sum += expf(v.x - m) + expf(v.y - m) + expf(v.z - m) + expf(v.w - m);
    }
    rm[tid] = m; rs[tid] = sum; __syncthreads();
    for (int t = 128; t; t >>= 1) {
        if (tid < t) {
            const float m2 = rm[tid + t], s2 = rs[tid + t];
            const float M = fmaxf(rm[tid], m2);
            rs[tid] = rs[tid] * expf(rm[tid] - M) + s2 * expf(m2 - M);
            rm[tid] = M;
        }
        __syncthreads();
    }
    if (tid == 0) part[(size_t)b * LSE_CHUNKS + s] = make_float2(rm[0], rs[0]);
}

__global__ __launch_bounds__(128) void lse_final(const float2* __restrict__ part,
                                                 float* __restrict__ lse)
{
    const int b = threadIdx.x;
    float m = -__builtin_inff(), s = 0.f;
    #pragma unroll
    for (int i = 0; i < LSE_CHUNKS; i++) {
        const float2 p = part[(size_t)b * LSE_CHUNKS + i];
        const float M = fmaxf(m, p.x);
        s = s * expf(m - M) + p.y * expf(p.x - M);
        m = M;
    }
    lse[b] = m + logf(s);
}

// In-place: out[b][v] = (1 - pp[b]) * (logit - lse[b])
__global__ __launch_bounds__(256) void final_write(float* __restrict__ out,
                                                   const float* __restrict__ pp,
                                                   const float* __restrict__ lse)
{
    const int b = blockIdx.y;
    const int v = (blockIdx.x * 256 + threadIdx.x) * 4;
    if (v >= VV) return;
    float4* p = (float4*)(out + (size_t)b * VV + v);
    float4 x = *p;
    const float g = 1.f - pp[b];
    const float Lse = lse[b];
    x.x = g * (x.x - Lse);
    x.y = g * (x.y - Lse);
    x.z = g * (x.z - Lse);
    x.w = g * (x.w - Lse);
    *p = x;
}

// Scatter pointer mass: out[b][enc_in[l][b]] += pp[b] * alpha_e[b][l]
__global__ __launch_bounds__(256) void scatter_pointer(float* __restrict__ out,
                                                       const float* __restrict__ pp,
                                                       const float* __restrict__ alpha_e,
                                                       const int* __restrict__ enc_in)
{
    const int idx = blockIdx.x * 256 + threadIdx.x;
    if (idx >= BB * LL) return;
    const int b = idx / LL;
    const int l = idx - b * LL;
    const int tok = enc_in[(size_t)l * BB + b];
    atomicAdd(&out[(size_t)b * VV + tok], pp[b] * alpha_e[idx]);
}

__global__ __launch_bounds__(256) void copy_pw(float* __restrict__ dst,
                                               const float* __restrict__ src)
{
    const int idx = blockIdx.x * 256 + threadIdx.x;
    if (idx < BB * LL) dst[idx] = src[idx];
}

// ---------------------------------------------------------------------------
extern "C" void kernel_launch(void* const* d_in, const int* in_sizes, int n_in,
                              void* d_out, int out_size, void* d_ws, size_t ws_size,
                              hipStream_t stream)
{
    const int*   inputs  = (const int*)  d_in[0];
    const float* hidden  = (const float*)d_in[1];
    const float* enc_h   = (const float*)d_in[2];
    const int*   enc_len = (const int*)  d_in[3];
    const float* prev_w  = (const float*)d_in[4];
    const float* dec_h   = (const float*)d_in[5];
    const int*   enc_in  = (const int*)  d_in[6];
    const float* emb     = (const float*)d_in[8];
    const float* W_ih    = (const float*)d_in[9];
    const float* W_hh    = (const float*)d_in[10];
    const float* b_ih    = (const float*)d_in[11];
    const float* b_hh    = (const float*)d_in[12];
    const float* W_ae    = (const float*)d_in[13];
    const float* b_ae    = (const float*)d_in[14];
    const float* W_ad    = (const float*)d_in[15];
    const float* b_ad    = (const float*)d_in[16];
    const float* W_ptr   = (const float*)d_in[17];
    const float* b_ptr   = (const float*)d_in[18];
    const float* W_out   = (const float*)d_in[19];
    const float* b_out   = (const float*)d_in[20];

    float* out = (float*)d_out;
    float* out_final = out;                              // B*V
    float* out_h     = out + (size_t)BB * VV;            // B*H
    float* out_pw    = out_h + (size_t)BB * HH;          // B*L

    // Workspace layout (floats)
    float* ws  = (float*)d_ws;
    float* X   = ws;                 // B*E
    float* GI  = X   + BB * EE;      // B*3H
    float* GH  = GI  + BB * H3;      // B*3H
    float* TE  = GH  + BB * H3;      // B*H
    float* TD  = TE  + BB * HH;      // B*H
    float* AE  = TD  + BB * HH;      // B*L
    float* AD  = AE  + BB * LL;      // B*T
    float* NH  = AD  + BB * TT;      // B*3H  (c_t_e | h | c_t_d)
    float* PP  = NH  + BB * H3;      // B
    float* LSE = PP  + BB;           // B
    float2* PART = (float2*)(LSE + BB);              // B * LSE_CHUNKS
    unsigned short* ABF = (unsigned short*)(PART + BB * LSE_CHUNKS);  // B*3H bf16

    // 1. embedding gather + zero context slices
    gather_emb<<<BB, 256, 0, stream>>>(inputs, emb, X);
    zero_ctx<<<BB, 256, 0, stream>>>(NH);

    // 2. GRU gate GEMMs (paired)
    {
        GemmJob jgi{X,      W_ih, b_ih, GI, EE, EE};
        GemmJob jgh{hidden, W_hh, b_hh, GH, HH, HH};
        gemm_m128<<<dim3(H3 / GBN, 2), 256, 0, stream>>>(jgi, jgh, H3, H3);
    }
    // 3. GRU combine
    gru_combine<<<BB, 256, 0, stream>>>(GI, GH, hidden, NH, out_h);

    // 4. attention query projections (paired)
    {
        GemmJob jte{NH + 512, W_ae, b_ae, TE, H3, HH};
        GemmJob jtd{NH + 512, W_ad, b_ad, TD, H3, HH};
        gemm_m128<<<dim3(HH / GBN, 2), 256, 0, stream>>>(jte, jtd, HH, HH);
    }

    // 5. attention scores
    attn_scores<<<dim3(LL / 4, BB), 256, 0, stream>>>(TE, enc_h, enc_len, AE, LL);
    attn_scores<<<dim3(TT / 4, BB), 256, 0, stream>>>(TD, dec_h, nullptr, AD, TT);

    // 6. softmaxes
    softmax2<<<dim3(BB, 2), 256, 0, stream>>>(AE, LL, AD, TT);

    // 7. context vectors (chunk = 25)
    attn_context<<<dim3(LL / 25, BB), 256, 0, stream>>>(AE, enc_h, NH, LL, 25, 0);
    attn_context<<<dim3(TT / 25, BB), 256, 0, stream>>>(AD, dec_h, NH, TT, 25, 1024);

    // 8. pointer prob
    pointer_kernel<<<BB, 256, 0, stream>>>(NH, W_ptr, b_ptr, PP);

    // 9. vocab GEMM (bf16 MFMA) -> logits into d_out
    nh_to_bf16<<<(BB * H3) / 256, 256, 0, stream>>>(NH, ABF);
    vocab_mfma<<<(VV + 63) / 64, 256, 0, stream>>>(ABF, W_out, b_out, out_final);

    // 10. two-stage logsumexp, then in-place final combine
    lse_part<<<dim3(LSE_CHUNKS, BB), 256, 0, stream>>>(out_final, PART);
    lse_final<<<1, 128, 0, stream>>>(PART, LSE);
    final_write<<<dim3((VV / 4 + 255) / 256, BB), 256, 0, stream>>>(out_final, PP, LSE);

    // 11. pointer scatter-add
    scatter_pointer<<<(BB * LL) / 256, 256, 0, stream>>>(out_final, PP, AE, enc_in);

    // 12. previous_weights passthrough
    copy_pw<<<(BB * LL) / 256, 256, 0, stream>>>(out_pw, prev_w);
}

// Round 3
// 875.207 us; speedup vs baseline: 1.2284x; 1.0370x over previous
//
#include <hip/hip_runtime.h>
#include <cstdint>
#include <cstddef>

// Problem constants
#define VV 50000
#define EE 256
#define HH 512
#define BB 128
#define LL 400
#define TT 100
#define H3 1536

typedef __attribute__((ext_vector_type(8))) short short8;
typedef __attribute__((ext_vector_type(4))) float floatx4;

__device__ __forceinline__ unsigned short f2bf(float x) {
    union { float f; unsigned u; } v; v.f = x;
    unsigned r = v.u + 0x7fffu + ((v.u >> 16) & 1u);
    return (unsigned short)(r >> 16);
}

// Pack two floats to two bf16 (round-half-up) in one dword via v_perm.
__device__ __forceinline__ unsigned bfpack(float x, float y) {
    union { float f; unsigned u; } a, b;
    a.f = x; b.f = y;
    const unsigned lo = a.u + 0x8000u;
    const unsigned hi = b.u + 0x8000u;
    return __builtin_amdgcn_perm(hi, lo, 0x07060302u);
}

// ---------------------------------------------------------------------------
// Small fp32 GEMM (GRU gates, attention projections): C = bias + A * W^T
// ---------------------------------------------------------------------------
struct GemmJob {
    const float* A;
    const float* W;
    const float* bias;
    float*       C;
    int          lda;
    int          K;
};

#define GBN 64
#define GBK 32

__global__ __launch_bounds__(256) void gemm_m128(GemmJob j0, GemmJob j1,
                                                 int N, int ldc)
{
    GemmJob j = (blockIdx.y == 0) ? j0 : j1;
    __shared__ float As[GBK][128];
    __shared__ float Wls[GBK][GBN];

    const int tid = threadIdx.x;
    const int n0  = blockIdx.x * GBN;
    const int tx  = tid & 15;
    const int ty  = tid >> 4;
    const int kq  = tid & 7;
    const int arow = (tid >> 3) * 4;
    const int wrow = (tid >> 3) * 2;

    float acc[8][4];
    #pragma unroll
    for (int i = 0; i < 8; i++)
        #pragma unroll
        for (int jj = 0; jj < 4; jj++) acc[i][jj] = 0.f;

    for (int k0 = 0; k0 < j.K; k0 += GBK) {
        #pragma unroll
        for (int i = 0; i < 4; i++) {
            const float4 v = *(const float4*)(j.A + (size_t)(arow + i) * j.lda + k0 + kq * 4);
            As[kq*4+0][arow+i] = v.x;
            As[kq*4+1][arow+i] = v.y;
            As[kq*4+2][arow+i] = v.z;
            As[kq*4+3][arow+i] = v.w;
        }
        #pragma unroll
        for (int i = 0; i < 2; i++) {
            const int n = n0 + wrow + i;
            float4 v = make_float4(0.f, 0.f, 0.f, 0.f);
            if (n < N) v = *(const float4*)(j.W + (size_t)n * j.K + k0 + kq * 4);
            Wls[kq*4+0][wrow+i] = v.x;
            Wls[kq*4+1][wrow+i] = v.y;
            Wls[kq*4+2][wrow+i] = v.z;
            Wls[kq*4+3][wrow+i] = v.w;
        }
        __syncthreads();
        #pragma unroll
        for (int kk = 0; kk < GBK; kk++) {
            float a[8], w[4];
            #pragma unroll
            for (int i = 0; i < 8; i++) a[i] = As[kk][ty*8+i];
            #pragma unroll
            for (int jj = 0; jj < 4; jj++) w[jj] = Wls[kk][tx*4+jj];
            #pragma unroll
            for (int i = 0; i < 8; i++)
                #pragma unroll
                for (int jj = 0; jj < 4; jj++)
                    acc[i][jj] += a[i] * w[jj];
        }
        __syncthreads();
    }

    const int nbase = n0 + tx * 4;
    #pragma unroll
    for (int i = 0; i < 8; i++) {
        const int b = ty * 8 + i;
        if (nbase + 3 < N) {
            const float4 bb = *(const float4*)(j.bias + nbase);
            float4 r;
            r.x = acc[i][0] + bb.x;
            r.y = acc[i][1] + bb.y;
            r.z = acc[i][2] + bb.z;
            r.w = acc[i][3] + bb.w;
            *(float4*)(j.C + (size_t)b * ldc + nbase) = r;
        } else {
            #pragma unroll
            for (int jj = 0; jj < 4; jj++) {
                const int n = nbase + jj;
                if (n < N) j.C[(size_t)b * ldc + n] = acc[i][jj] + j.bias[n];
            }
        }
    }
}

// ---------------------------------------------------------------------------
// Vocab GEMM: bf16 MFMA, no LDS, register-double-buffered K loop.
// A: [128][1536] bf16 (L2-resident). W: [V][1536] f32 from HBM.
// Wave = 16-wide n strip x all 128 m. Prefetch next iter's W+A during MFMA.
// ---------------------------------------------------------------------------
__global__ __launch_bounds__(256) void vocab_mfma(const unsigned short* __restrict__ A,
                                                  const float* __restrict__ W,
                                                  const float* __restrict__ bias,
                                                  float* __restrict__ C)
{
    const int wave = threadIdx.x >> 6;
    const int lane = threadIdx.x & 63;
    const int quad = lane >> 4;   // 0..3
    const int nl   = lane & 15;
    const int n    = blockIdx.x * 64 + wave * 16 + nl;
    const int nc   = (n < VV) ? n : (VV - 1);

    floatx4 acc[8];
    #pragma unroll
    for (int i = 0; i < 8; i++) acc[i] = (floatx4){0.f, 0.f, 0.f, 0.f};

    const float* wp = W + (size_t)nc * H3 + quad * 8;
    const unsigned short* ap = A + (size_t)nl * H3 + quad * 8;

    // Prologue: load iteration 0
    float4 cw0 = *(const float4*)(wp);
    float4 cw1 = *(const float4*)(wp + 4);
    short8 caf[8];
    #pragma unroll
    for (int mt = 0; mt < 8; mt++)
        caf[mt] = *(const short8*)(ap + (size_t)mt * 16 * H3);

    for (int k0 = 0; k0 < H3; k0 += 32) {
        // Prefetch next iteration (clamped so last iter reads valid addrs)
        int k1 = k0 + 32;
        k1 = (k1 < H3) ? k1 : 0;
        const float4 nw0 = *(const float4*)(wp + k1);
        const float4 nw1 = *(const float4*)(wp + k1 + 4);
        short8 naf[8];
        #pragma unroll
        for (int mt = 0; mt < 8; mt++)
            naf[mt] = *(const short8*)(ap + (size_t)mt * 16 * H3 + k1);

        // Convert current W to bf16 (v_perm pack)
        int4 bi;
        bi.x = (int)bfpack(cw0.x, cw0.y);
        bi.y = (int)bfpack(cw0.z, cw0.w);
        bi.z = (int)bfpack(cw1.x, cw1.y);
        bi.w = (int)bfpack(cw1.z, cw1.w);
        const short8 bf = *(const short8*)&bi;

        #pragma unroll
        for (int mt = 0; mt < 8; mt++)
            acc[mt] = __builtin_amdgcn_mfma_f32_16x16x32_bf16(caf[mt], bf, acc[mt], 0, 0, 0);

        // Rotate buffers
        cw0 = nw0; cw1 = nw1;
        #pragma unroll
        for (int mt = 0; mt < 8; mt++) caf[mt] = naf[mt];
    }

    if (n < VV) {
        const float bv = bias[n];
        #pragma unroll
        for (int mt = 0; mt < 8; mt++) {
            #pragma unroll
            for (int r = 0; r < 4; r++) {
                const int m = mt * 16 + quad * 4 + r;
                C[(size_t)m * VV + n] = acc[mt][r] + bv;
            }
        }
    }
}

// ---------------------------------------------------------------------------
// Fused: embedding gather + zero context slices of NH
// ---------------------------------------------------------------------------
__global__ __launch_bounds__(256) void prep(const int* __restrict__ tok,
                                            const float* __restrict__ emb,
                                            float* __restrict__ x,
                                            float* __restrict__ nh)
{
    const int b = blockIdx.x;
    const int tid = threadIdx.x;
    x[(size_t)b * EE + tid] = emb[(size_t)tok[b] * EE + tid];
    float* p = nh + (size_t)b * H3;
    p[tid] = 0.f;  p[tid + 256] = 0.f;
    p[1024 + tid] = 0.f;  p[1280 + tid] = 0.f;
}

// ---------------------------------------------------------------------------
// GRU pointwise combine
// ---------------------------------------------------------------------------
__global__ __launch_bounds__(256) void gru_combine(const float* __restrict__ gi,
                                                   const float* __restrict__ gh,
                                                   const float* __restrict__ hprev,
                                                   float* __restrict__ nh,
                                                   float* __restrict__ out_h)
{
    const int b = blockIdx.x;
    const int tid = threadIdx.x;
    #pragma unroll
    for (int r = 0; r < 2; r++) {
        const int i = tid + r * 256;
        const size_t base = (size_t)b * H3;
        const float ir = gi[base + i],        hr = gh[base + i];
        const float iz = gi[base + 512 + i],  hz = gh[base + 512 + i];
        const float in_ = gi[base + 1024 + i], hn = gh[base + 1024 + i];
        const float rr = 1.f / (1.f + expf(-(ir + hr)));
        const float zz = 1.f / (1.f + expf(-(iz + hz)));
        const float nn = tanhf(in_ + rr * hn);
        const float hp = hprev[(size_t)b * HH + i];
        const float h  = (1.f - zz) * nn + zz * hp;
        nh[base + 512 + i] = h;
        out_h[(size_t)b * HH + i] = h;
    }
}

// ---------------------------------------------------------------------------
// Fused attention scores (enc: x<100, dec: x>=100). One wave per (b,l).
// ---------------------------------------------------------------------------
__global__ __launch_bounds__(256) void attn_scores2(const float* __restrict__ qe,
                                                    const float* __restrict__ ctxe,
                                                    const int* __restrict__ lens,
                                                    float* __restrict__ oute,
                                                    const float* __restrict__ qd,
                                                    const float* __restrict__ ctxd,
                                                    float* __restrict__ outd)
{
    const int b = blockIdx.y;
    const int wave = threadIdx.x >> 6;
    const int lane = threadIdx.x & 63;

    const float* q;
    const float* c;
    float* o;
    int l, Lc;
    bool mask;
    if (blockIdx.x < 100) {
        l = blockIdx.x * 4 + wave; Lc = LL;
        q = qe; c = ctxe; o = oute; mask = true;
    } else {
        l = (blockIdx.x - 100) * 4 + wave; Lc = TT;
        q = qd; c = ctxd; o = outd; mask = false;
    }

    const float4* q4 = (const float4*)(q + (size_t)b * HH);
    const float4* c4 = (const float4*)(c + ((size_t)l * BB + b) * HH);
    const float4 a0 = q4[lane],      b0 = c4[lane];
    const float4 a1 = q4[lane + 64], b1 = c4[lane + 64];
    float s = a0.x*b0.x + a0.y*b0.y + a0.z*b0.z + a0.w*b0.w
            + a1.x*b1.x + a1.y*b1.y + a1.z*b1.z + a1.w*b1.w;
    #pragma unroll
    for (int off = 32; off; off >>= 1)
        s += __shfl_down(s, off);
    if (lane == 0) {
        if (mask && (Lc < lens[b]) && (l >= lens[b])) s = -__builtin_inff();
        o[(size_t)b * Lc + l] = s;
    }
}

// In-place row softmax for alpha_e (y=0) and alpha_d (y=1)
__global__ __launch_bounds__(256) void softmax2(float* __restrict__ ae, int ne,
                                                float* __restrict__ ad, int nd)
{
    __shared__ float red[256];
    const int tid = threadIdx.x;
    float* row;
    int n;
    if (blockIdx.y == 0) { row = ae + (size_t)blockIdx.x * ne; n = ne; }
    else                 { row = ad + (size_t)blockIdx.x * nd; n = nd; }

    float m = -__builtin_inff();
    for (int i = tid; i < n; i += 256) m = fmaxf(m, row[i]);
    red[tid] = m; __syncthreads();
    for (int s = 128; s; s >>= 1) {
        if (tid < s) red[tid] = fmaxf(red[tid], red[tid + s]);
        __syncthreads();
    }
    m = red[0]; __syncthreads();

    float sum = 0.f;
    for (int i = tid; i < n; i += 256) sum += expf(row[i] - m);
    red[tid] = sum; __syncthreads();
    for (int s = 128; s; s >>= 1) {
        if (tid < s) red[tid] += red[tid + s];
        __syncthreads();
    }
    const float inv = 1.f / red[0];
    for (int i = tid; i < n; i += 256) row[i] = expf(row[i] - m) * inv;
}

// Fused context vectors (enc chunks x<16, dec chunks x>=16), chunk = 25
__global__ __launch_bounds__(256) void attn_context2(const float* __restrict__ ae,
                                                     const float* __restrict__ ctxe,
                                                     const float* __restrict__ ad,
                                                     const float* __restrict__ ctxd,
                                                     float* __restrict__ dst)
{
    __shared__ float al[32];
    const int b = blockIdx.y;
    const int tid = threadIdx.x;

    const float* alpha;
    const float* ctx;
    int l0, Lc, off;
    if (blockIdx.x < 16) {
        l0 = blockIdx.x * 25; Lc = LL; off = 0;
        alpha = ae; ctx = ctxe;
    } else {
        l0 = (blockIdx.x - 16) * 25; Lc = TT; off = 1024;
        alpha = ad; ctx = ctxd;
    }

    if (tid < 25) al[tid] = alpha[(size_t)b * Lc + l0 + tid];
    __syncthreads();
    float ax = 0.f, ay = 0.f;
    #pragma unroll 5
    for (int ll = 0; ll < 25; ll++) {
        const float2* c = (const float2*)(ctx + ((size_t)(l0 + ll) * BB + b) * HH);
        const float2 v = c[tid];
        const float w = al[ll];
        ax += w * v.x;
        ay += w * v.y;
    }
    atomicAdd(&dst[(size_t)b * H3 + off + tid * 2 + 0], ax);
    atomicAdd(&dst[(size_t)b * H3 + off + tid * 2 + 1], ay);
}

// Fused: pointer_prob[b] = dot(nh[b], W_ptr) + b_ptr  AND  NH -> bf16
__global__ __launch_bounds__(256) void pointer_bf16(const float* __restrict__ nh,
                                                    const float* __restrict__ W_ptr,
                                                    const float* __restrict__ b_ptr,
                                                    float* __restrict__ pp,
                                                    unsigned short* __restrict__ abf)
{
    __shared__ float red[256];
    const int b = blockIdx.x;
    const int tid = threadIdx.x;
    float s = 0.f;
    #pragma unroll
    for (int r = 0; r < 6; r++) {
        const int jj = tid + r * 256;
        const float v = nh[(size_t)b * H3 + jj];
        abf[(size_t)b * H3 + jj] = f2bf(v);
        s += v * W_ptr[jj];
    }
    red[tid] = s; __syncthreads();
    for (int t = 128; t; t >>= 1) {
        if (tid < t) red[tid] += red[tid + t];
        __syncthreads();
    }
    if (tid == 0) pp[b] = red[0] + b_ptr[0];
}

// ---------------------------------------------------------------------------
// Two-stage logsumexp over V
// ---------------------------------------------------------------------------
#define LSE_CHUNKS 10
#define LSE_SPAN 5000   // 1250 float4s

__global__ __launch_bounds__(256) void lse_part(const float* __restrict__ logits,
                                                float2* __restrict__ part)
{
    __shared__ float rm[256], rs[256];
    const int b = blockIdx.y;
    const int s = blockIdx.x;
    const int tid = threadIdx.x;
    const float4* row = (const float4*)(logits + (size_t)b * VV + (size_t)s * LSE_SPAN);
    float m = -__builtin_inff(), sum = 0.f;
    for (int i = tid; i < LSE_SPAN / 4; i += 256) {
        const float4 v = row[i];
        const float mx = fmaxf(fmaxf(v.x, v.y), fmaxf(v.z, v.w));
        if (mx > m) { sum *= expf(m - mx); m = mx; }
        sum += expf(v.x - m) + expf(v.y - m) + expf(v.z - m) + expf(v.w - m);
    }
    rm[tid] = m; rs[tid] = sum; __syncthreads();
    for (int t = 128; t; t >>= 1) {
        if (tid < t) {
            const float m2 = rm[tid + t], s2 = rs[tid + t];
            const float M = fmaxf(rm[tid], m2);
            rs[tid] = rs[tid] * expf(rm[tid] - M) + s2 * expf(m2 - M);
            rm[tid] = M;
        }
        __syncthreads();
    }
    if (tid == 0) part[(size_t)b * LSE_CHUNKS + s] = make_float2(rm[0], rs[0]);
}

// In-place: out[b][v] = (1 - pp[b]) * (logit - lse[b]); lse reduced from parts
// (broadcast loads: all lanes read the same 10 float2s -> L1 broadcast)
__global__ __launch_bounds__(256) void final_write(float* __restrict__ out,
                                                   const float* __restrict__ pp,
                                                   const float2* __restrict__ part)
{
    const int b = blockIdx.y;
    float m = -__builtin_inff(), s = 0.f;
    #pragma unroll
    for (int i = 0; i < LSE_CHUNKS; i++) {
        const float2 p = part[(size_t)b * LSE_CHUNKS + i];
        const float M = fmaxf(m, p.x);
        s = s * expf(m - M) + p.y * expf(p.x - M);
        m = M;
    }
    const float Lse = m + logf(s);

    const int v = (blockIdx.x * 256 + threadIdx.x) * 4;
    if (v >= VV) return;
    float4* p = (float4*)(out + (size_t)b * VV + v);
    float4 x = *p;
    const float g = 1.f - pp[b];
    x.x = g * (x.x - Lse);
    x.y = g * (x.y - Lse);
    x.z = g * (x.z - Lse);
    x.w = g * (x.w - Lse);
    *p = x;
}

// Fused: pointer scatter-add + previous_weights passthrough
__global__ __launch_bounds__(256) void scatter_copy(float* __restrict__ out,
                                                    const float* __restrict__ pp,
                                                    const float* __restrict__ alpha_e,
                                                    const int* __restrict__ enc_in,
                                                    float* __restrict__ pw_dst,
                                                    const float* __restrict__ pw_src)
{
    const int idx = blockIdx.x * 256 + threadIdx.x;
    if (idx >= BB * LL) return;
    pw_dst[idx] = pw_src[idx];
    const int b = idx / LL;
    const int l = idx - b * LL;
    const int tok = enc_in[(size_t)l * BB + b];
    atomicAdd(&out[(size_t)b * VV + tok], pp[b] * alpha_e[idx]);
}

// ---------------------------------------------------------------------------
extern "C" void kernel_launch(void* const* d_in, const int* in_sizes, int n_in,
                              void* d_out, int out_size, void* d_ws, size_t ws_size,
                              hipStream_t stream)
{
    const int*   inputs  = (const int*)  d_in[0];
    const float* hidden  = (const float*)d_in[1];
    const float* enc_h   = (const float*)d_in[2];
    const int*   enc_len = (const int*)  d_in[3];
    const float* prev_w  = (const float*)d_in[4];
    const float* dec_h   = (const float*)d_in[5];
    const int*   enc_in  = (const int*)  d_in[6];
    const float* emb     = (const float*)d_in[8];
    const float* W_ih    = (const float*)d_in[9];
    const float* W_hh    = (const float*)d_in[10];
    const float* b_ih    = (const float*)d_in[11];
    const float* b_hh    = (const float*)d_in[12];
    const float* W_ae    = (const float*)d_in[13];
    const float* b_ae    = (const float*)d_in[14];
    const float* W_ad    = (const float*)d_in[15];
    const float* b_ad    = (const float*)d_in[16];
    const float* W_ptr   = (const float*)d_in[17];
    const float* b_ptr   = (const float*)d_in[18];
    const float* W_out   = (const float*)d_in[19];
    const float* b_out   = (const float*)d_in[20];

    float* out = (float*)d_out;
    float* out_final = out;                              // B*V
    float* out_h     = out + (size_t)BB * VV;            // B*H
    float* out_pw    = out_h + (size_t)BB * HH;          // B*L

    // Workspace layout (floats)
    float* ws  = (float*)d_ws;
    float* X   = ws;                 // B*E
    float* GI  = X   + BB * EE;      // B*3H
    float* GH  = GI  + BB * H3;      // B*3H
    float* TE  = GH  + BB * H3;      // B*H
    float* TD  = TE  + BB * HH;      // B*H
    float* AE  = TD  + BB * HH;      // B*L
    float* AD  = AE  + BB * LL;      // B*T
    float* NH  = AD  + BB * TT;      // B*3H  (c_t_e | h | c_t_d)
    float* PP  = NH  + BB * H3;      // B
    float* LSE = PP  + BB;           // B (unused now, kept for layout stability)
    float2* PART = (float2*)(LSE + BB);                               // B * 10
    unsigned short* ABF = (unsigned short*)(PART + BB * LSE_CHUNKS);  // B*3H bf16

    // 1. embedding gather + zero context slices
    prep<<<BB, 256, 0, stream>>>(inputs, emb, X, NH);

    // 2. GRU gate GEMMs (paired)
    {
        GemmJob jgi{X,      W_ih, b_ih, GI, EE, EE};
        GemmJob jgh{hidden, W_hh, b_hh, GH, HH, HH};
        gemm_m128<<<dim3(H3 / GBN, 2), 256, 0, stream>>>(jgi, jgh, H3, H3);
    }
    // 3. GRU combine
    gru_combine<<<BB, 256, 0, stream>>>(GI, GH, hidden, NH, out_h);

    // 4. attention query projections (paired)
    {
        GemmJob jte{NH + 512, W_ae, b_ae, TE, H3, HH};
        GemmJob jtd{NH + 512, W_ad, b_ad, TD, H3, HH};
        gemm_m128<<<dim3(HH / GBN, 2), 256, 0, stream>>>(jte, jtd, HH, HH);
    }

    // 5. attention scores (enc + dec fused)
    attn_scores2<<<dim3(125, BB), 256, 0, stream>>>(TE, enc_h, enc_len, AE,
                                                    TD, dec_h, AD);

    // 6. softmaxes
    softmax2<<<dim3(BB, 2), 256, 0, stream>>>(AE, LL, AD, TT);

    // 7. context vectors (enc + dec fused)
    attn_context2<<<dim3(20, BB), 256, 0, stream>>>(AE, enc_h, AD, dec_h, NH);

    // 8. pointer prob + NH -> bf16
    pointer_bf16<<<BB, 256, 0, stream>>>(NH, W_ptr, b_ptr, PP, ABF);

    // 9. vocab GEMM (bf16 MFMA, double-buffered) -> logits into d_out
    vocab_mfma<<<(VV + 63) / 64, 256, 0, stream>>>(ABF, W_out, b_out, out_final);

    // 10. logsumexp parts, then in-place final combine (lse folded in)
    lse_part<<<dim3(LSE_CHUNKS, BB), 256, 0, stream>>>(out_final, PART);
    final_write<<<dim3((VV / 4 + 255) / 256, BB), 256, 0, stream>>>(out_final, PP, PART);

    // 11. pointer scatter-add + previous_weights passthrough
    scatter_copy<<<(BB * LL) / 256, 256, 0, stream>>>(out_final, PP, AE, enc_in,
                                                      out_pw, prev_w);
}